// Round 1
// baseline (412.827 us; speedup 1.0000x reference)
//
#include <hip/hip_runtime.h>
#include <math.h>

#define S 2048
#define D 64
#define H 16
#define BR 64              // Q rows per block
#define BC 64              // K cols per tile
#define NIT (S / BC)       // 32 K-tiles
#define KSTR 72            // LDS row stride in bf16 elems (conflict-free b128 frag reads)

typedef __attribute__((ext_vector_type(8))) short bf16x8;
typedef __attribute__((ext_vector_type(4))) float f32x4;

__device__ __forceinline__ unsigned short f2bf(float x) {
    unsigned u = __float_as_uint(x);
    u += 0x7fffu + ((u >> 16) & 1u);          // RTNE
    return (unsigned short)(u >> 16);
}
__device__ __forceinline__ float bf2f(unsigned short h) {
    return __uint_as_float(((unsigned)h) << 16);
}

// Raw barrier discipline: publish LDS with lgkmcnt(0) only — attn stores and
// prefetched global loads stay in flight across barriers (no vmcnt(0) drain).
#define LGKM0() asm volatile("s_waitcnt lgkmcnt(0)" ::: "memory")
#define BAR()   __builtin_amdgcn_s_barrier()

// Fused attention with materialized attn output.
// All MFMAs use SWAPPED operands (A=K/V^T frag, B=Q/P frag) so each lane owns
// 4 consecutive fast-axis elements of the output -> f32x4 global stores,
// b64 P staging, lane-local softmax rows.
__global__ __launch_bounds__(256, 2)
void k_attn_fused(const float* __restrict__ Q, const float* __restrict__ K,
                  const float* __restrict__ V, float* __restrict__ ctx,
                  float* __restrict__ attn) {
    __shared__ __align__(16) unsigned short Qs[BR * KSTR];    // 9.2 KB
    __shared__ __align__(16) unsigned short Ks[BC * KSTR];    // 9.2 KB
    __shared__ __align__(16) unsigned short Vthi[D * KSTR];   // V^T hi: [d][k]
    __shared__ __align__(16) unsigned short Vtlo[D * KSTR];   // V^T lo
    __shared__ __align__(16) unsigned short Phi[BR * KSTR];   // P hi (A-layout rows [q][k])
    __shared__ __align__(16) unsigned short Plo[BR * KSTR];   // P lo
    // total 55.3 KB -> 2 blocks/CU

    const int h  = blockIdx.y;
    const int r0 = blockIdx.x * BR;
    const int t  = threadIdx.x;
    const int w    = t >> 6;        // wave 0..3 -> q rows [w*16, w*16+16)
    const int lane = t & 63;
    const int l16  = lane & 15;
    const int quad = lane >> 4;

    const float* Qh = Q + (size_t)h * S * D;
    const float* Kh = K + (size_t)h * S * D;
    const float* Vh = V + (size_t)h * S * D;

    // ---- stage Q tile (64x64 fp32 -> bf16 LDS), coalesced float4 ----
#pragma unroll
    for (int p = 0; p < 4; ++p) {
        int idx = t + p * 256;                 // 0..1023 float4s
        int r = idx >> 4, c4 = (idx & 15) * 4;
        float4 v = *(const float4*)(Qh + (size_t)(r0 + r) * D + c4);
        *(ushort4*)&Qs[r * KSTR + c4] =
            make_ushort4(f2bf(v.x), f2bf(v.y), f2bf(v.z), f2bf(v.w));
    }
    LGKM0(); BAR();

    // persistent Q frags (B-operand in swapped mode): row q = w*16+l16
    bf16x8 bq[2];
    bq[0] = *(const bf16x8*)&Qs[(w * 16 + l16) * KSTR + 0 * 32 + quad * 8];
    bq[1] = *(const bf16x8*)&Qs[(w * 16 + l16) * KSTR + 1 * 32 + quad * 8];

    const f32x4 zero4 = {0.f, 0.f, 0.f, 0.f};
    float lsum = 0.f;        // row sum for q = w*16+l16 (replicated across quads)

    // =================== Pass A: denominators ===================
    // register double-buffer: prefetch K tile kt+1 while computing tile kt
    float4 kreg[4];
#pragma unroll
    for (int p = 0; p < 4; ++p) {
        int idx = t + p * 256;
        int r = idx >> 4, c4 = (idx & 15) * 4;
        kreg[p] = *(const float4*)(Kh + (size_t)r * D + c4);
    }
    for (int kt = 0; kt < NIT; ++kt) {
        // LDS-write staged regs
#pragma unroll
        for (int p = 0; p < 4; ++p) {
            int idx = t + p * 256;
            int r = idx >> 4, c4 = (idx & 15) * 4;
            *(ushort4*)&Ks[r * KSTR + c4] =
                make_ushort4(f2bf(kreg[p].x), f2bf(kreg[p].y), f2bf(kreg[p].z), f2bf(kreg[p].w));
        }
        LGKM0(); BAR();
        // issue next-tile loads; latency hides under MFMA+exp below
        if (kt + 1 < NIT) {
#pragma unroll
            for (int p = 0; p < 4; ++p) {
                int idx = t + p * 256;
                int r = idx >> 4, c4 = (idx & 15) * 4;
                kreg[p] = *(const float4*)(Kh + (size_t)((kt + 1) * BC + r) * D + c4);
            }
        }
        // S^T = mfma(K-frag, Q-frag): lane holds k = cs*16+quad*4+reg at q = w*16+l16
        f32x4 acc[4] = {zero4, zero4, zero4, zero4};
#pragma unroll
        for (int ks = 0; ks < 2; ++ks)
#pragma unroll
            for (int cs = 0; cs < 4; ++cs) {
                bf16x8 ak = *(const bf16x8*)&Ks[(cs * 16 + l16) * KSTR + ks * 32 + quad * 8];
                acc[cs] = __builtin_amdgcn_mfma_f32_16x16x32_bf16(ak, bq[ks], acc[cs], 0, 0, 0);
            }
        float e = 0.f;
#pragma unroll
        for (int cs = 0; cs < 4; ++cs)
#pragma unroll
            for (int r2 = 0; r2 < 4; ++r2)
                e += __expf(acc[cs][r2] * 0.125f);
        e += __shfl_xor(e, 16);      // reduce over the 4 quads sharing this q row
        e += __shfl_xor(e, 32);
        lsum += e;
        BAR();                        // protect Ks before next-tile restage
    }
    const float linv = 1.0f / lsum;

    // =================== Pass B: attn write + P@V ===================
    f32x4 cacc[4] = {zero4, zero4, zero4, zero4};   // ctx^T: lane owns q=w*16+l16, d=vs*16+quad*4+reg
    float4 vreg[4];
#pragma unroll
    for (int p = 0; p < 4; ++p) {
        int idx = t + p * 256;
        int r = idx >> 4, c4 = (idx & 15) * 4;
        kreg[p] = *(const float4*)(Kh + (size_t)r * D + c4);
        vreg[p] = *(const float4*)(Vh + (size_t)r * D + c4);
    }
    for (int kt = 0; kt < NIT; ++kt) {
        // stage K tile + V tile transposed hi/lo from prefetched regs
#pragma unroll
        for (int p = 0; p < 4; ++p) {
            int idx = t + p * 256;
            int r = idx >> 4, c4 = (idx & 15) * 4;   // K: r=row,c4=col; V: r=k, c4=d
            *(ushort4*)&Ks[r * KSTR + c4] =
                make_ushort4(f2bf(kreg[p].x), f2bf(kreg[p].y), f2bf(kreg[p].z), f2bf(kreg[p].w));
            float vv[4] = {vreg[p].x, vreg[p].y, vreg[p].z, vreg[p].w};
#pragma unroll
            for (int c = 0; c < 4; ++c) {
                unsigned short hi = f2bf(vv[c]);
                Vthi[(c4 + c) * KSTR + r] = hi;
                Vtlo[(c4 + c) * KSTR + r] = f2bf(vv[c] - bf2f(hi));
            }
        }
        LGKM0(); BAR();
        // prefetch next K/V tiles; latency hides under QK^T + softmax + PV
        if (kt + 1 < NIT) {
#pragma unroll
            for (int p = 0; p < 4; ++p) {
                int idx = t + p * 256;
                int r = idx >> 4, c4 = (idx & 15) * 4;
                kreg[p] = *(const float4*)(Kh + (size_t)((kt + 1) * BC + r) * D + c4);
                vreg[p] = *(const float4*)(Vh + (size_t)((kt + 1) * BC + r) * D + c4);
            }
        }
        // recompute S^T tile (swapped operands)
        f32x4 acc[4] = {zero4, zero4, zero4, zero4};
#pragma unroll
        for (int ks = 0; ks < 2; ++ks)
#pragma unroll
            for (int cs = 0; cs < 4; ++cs) {
                bf16x8 ak = *(const bf16x8*)&Ks[(cs * 16 + l16) * KSTR + ks * 32 + quad * 8];
                acc[cs] = __builtin_amdgcn_mfma_f32_16x16x32_bf16(ak, bq[ks], acc[cs], 0, 0, 0);
            }

        // normalize; f32x4 nontemporal attn store; b64 P staging in A-layout [q][k]
        float* arow = attn + (size_t)(h * S + r0 + w * 16 + l16) * S + (size_t)kt * BC;
        const int prow = (w * 16 + l16) * KSTR;
#pragma unroll
        for (int cs = 0; cs < 4; ++cs) {
            f32x4 pv;
#pragma unroll
            for (int r2 = 0; r2 < 4; ++r2)
                pv[r2] = __expf(acc[cs][r2] * 0.125f) * linv;
            __builtin_nontemporal_store(pv, (f32x4*)(arow + cs * 16 + quad * 4));
            unsigned short h0 = f2bf(pv[0]), h1 = f2bf(pv[1]),
                           h2 = f2bf(pv[2]), h3 = f2bf(pv[3]);
            *(ushort4*)&Phi[prow + cs * 16 + quad * 4] = make_ushort4(h0, h1, h2, h3);
            *(ushort4*)&Plo[prow + cs * 16 + quad * 4] =
                make_ushort4(f2bf(pv[0] - bf2f(h0)), f2bf(pv[1] - bf2f(h1)),
                             f2bf(pv[2] - bf2f(h2)), f2bf(pv[3] - bf2f(h3)));
        }
        // P staging is intra-wave (row w*16+l16 written & read only by wave w):
        // no __syncthreads needed, compiler orders ds_write->ds_read via lgkmcnt.
        asm volatile("" ::: "memory");

        // P @ V swapped: cacc = mfma(V^T-frag, P-frag) -> lane owns 4 consecutive d
#pragma unroll
        for (int ks = 0; ks < 2; ++ks) {
            bf16x8 ah = *(const bf16x8*)&Phi[prow + ks * 32 + quad * 8];
            bf16x8 al = *(const bf16x8*)&Plo[prow + ks * 32 + quad * 8];
#pragma unroll
            for (int vs = 0; vs < 4; ++vs) {
                bf16x8 bh = *(const bf16x8*)&Vthi[(vs * 16 + l16) * KSTR + ks * 32 + quad * 8];
                bf16x8 bl = *(const bf16x8*)&Vtlo[(vs * 16 + l16) * KSTR + ks * 32 + quad * 8];
                cacc[vs] = __builtin_amdgcn_mfma_f32_16x16x32_bf16(bh, ah, cacc[vs], 0, 0, 0);
                cacc[vs] = __builtin_amdgcn_mfma_f32_16x16x32_bf16(bl, ah, cacc[vs], 0, 0, 0);
                cacc[vs] = __builtin_amdgcn_mfma_f32_16x16x32_bf16(bh, al, cacc[vs], 0, 0, 0);
            }
        }
        BAR();   // protect Ks/Vt before next-tile restage (frag reads already consumed)
    }

    // epilogue: ctx store, f32x4 per lane (lane owns q row, 4 consecutive d)
    float* crow = ctx + (size_t)(h * S + r0 + w * 16 + l16) * D;
#pragma unroll
    for (int vs = 0; vs < 4; ++vs)
        *(f32x4*)(crow + vs * 16 + quad * 4) = cacc[vs];
}

extern "C" void kernel_launch(void* const* d_in, const int* in_sizes, int n_in,
                              void* d_out, int out_size, void* d_ws, size_t ws_size,
                              hipStream_t stream) {
    (void)in_sizes; (void)n_in; (void)d_ws; (void)ws_size; (void)out_size;
    const float* Q = (const float*)d_in[0];
    const float* K = (const float*)d_in[1];
    const float* V = (const float*)d_in[2];
    float* ctx  = (float*)d_out;                          // [16,2048,64]
    float* attn = (float*)d_out + (size_t)H * S * D;      // [16,2048,2048]

    k_attn_fused<<<dim3(S / BR, H), 256, 0, stream>>>(Q, K, V, ctx, attn);
}